// Round 1
// baseline (49.697 us; speedup 1.0000x reference)
//
#include <hip/hip_runtime.h>

// QuantumVelocityField: fused 4->128->128->6 silu MLP (fp16 MFMA, fp32 accum)
// + 3-layer RY/RZ single-qubit sim. B = 262144.
//
// All layers computed transposed: D = W^T · h^T, W = A-operand, h = B-operand
// of v_mfma_f32_16x16x32_f16. C/D layout (col = lane&15 = batch row,
// row = 4*(lane>>4)+reg = hidden idx) means acc of layer i IS the B-fragment
// of layer i+1 after bias+silu, purely in-register (sigma-permutation trick:
// A and B only need to agree on the (quarter,reg)->k bijection; W2/W3 are
// staged pre-permuted to match the accumulator ordering).

typedef _Float16 half8 __attribute__((ext_vector_type(8)));
typedef float f32x4 __attribute__((ext_vector_type(4)));

#define TILES_PER_BLOCK 4
#define NBLOCKS 512  // 512*4 tiles * 128 rows = 262144

__device__ __forceinline__ float silu_f(float x) {
    return __fdividef(x, 1.0f + __expf(-x));
}

__global__ __launch_bounds__(256, 2)
void qvf_kernel(const float* __restrict__ tg, const float* __restrict__ blg,
                const float* __restrict__ W1g, const float* __restrict__ b1g,
                const float* __restrict__ W2g, const float* __restrict__ b2g,
                const float* __restrict__ W3g, const float* __restrict__ b3g,
                float* __restrict__ out) {
    // W2 fp16, transposed to [n2][k'], k' = 32s+8q+4hi+c <-> k = 32s+16hi+4q+c,
    // XOR-swizzled (halfword idx ^ (n2&7)<<3) for conflict-free ds_read_b128.
    __shared__ __align__(16) _Float16 sW2p[16384];
    __shared__ __align__(16) float sB1[128];
    __shared__ __align__(16) float sB2[128];
    __shared__ float sP[4][32][9];  // per-wave param bounce, stride 9 = conflict-free

    const int tid  = threadIdx.x;
    const int w    = tid >> 6;
    const int lane = tid & 63;
    const int q    = lane >> 4;
    const int ln   = lane & 15;

    // ---- stage W2 (permute + swizzle + fp16) and biases ----
    for (int i = tid; i < 16384; i += 256) {
        int k = i >> 7, n2 = i & 127;          // coalesced read
        float wv = W2g[i];
        int s = k >> 5, hi = (k >> 4) & 1, qq = (k >> 2) & 3, c = k & 3;
        int kp = s * 32 + qq * 8 + hi * 4 + c;
        sW2p[n2 * 128 + (kp ^ ((n2 & 7) << 3))] = (_Float16)wv;
    }
    if (tid < 128) { sB1[tid] = b1g[tid]; sB2[tid] = b2g[tid]; }

    // ---- per-lane cached weight fragments (reused for all tiles) ----
    half8 W1c[8];
    #pragma unroll
    for (int nt = 0; nt < 8; ++nt) {
        half8 v = {};
        if (q == 0) {
            int n1 = nt * 16 + ln;
            #pragma unroll
            for (int j = 0; j < 4; ++j) v[j] = (_Float16)W1g[j * 128 + n1];
        }
        W1c[nt] = v;
    }
    half8 W3c[4];
    #pragma unroll
    for (int s = 0; s < 4; ++s) {
        half8 v = {};
        if (ln < 6) {
            #pragma unroll
            for (int j = 0; j < 8; ++j) {
                int k = s * 32 + (j >> 2) * 16 + q * 4 + (j & 3);
                v[j] = (_Float16)W3g[k * 6 + ln];
            }
        }
        W3c[s] = v;
    }
    float b3c[4];
    #pragma unroll
    for (int r = 0; r < 4; ++r) {
        int n3 = q * 4 + r;
        b3c[r] = (n3 < 6) ? b3g[n3] : 0.0f;
    }

    __syncthreads();

    for (int tt = 0; tt < TILES_PER_BLOCK; ++tt) {
        const int tile = blockIdx.x * TILES_PER_BLOCK + tt;
        const int rowb = tile * 128 + w * 32;   // this wave's 32 batch rows

        // ---- layer-1 B fragments: inp = [t, bloch] in k-slots 0..3 (q==0) ----
        half8 bf1[2] = {{}, {}};
        if (q == 0) {
            #pragma unroll
            for (int mt = 0; mt < 2; ++mt) {
                int m = rowb + mt * 16 + ln;
                bf1[mt][0] = (_Float16)tg[m];
                bf1[mt][1] = (_Float16)blg[3 * m + 0];
                bf1[mt][2] = (_Float16)blg[3 * m + 1];
                bf1[mt][3] = (_Float16)blg[3 * m + 2];
            }
        }

        // ---- layer 1: D1[n1][m] ----
        f32x4 acc1[2][8];
        #pragma unroll
        for (int nt = 0; nt < 8; ++nt) {
            acc1[0][nt] = __builtin_amdgcn_mfma_f32_16x16x32_f16(W1c[nt], bf1[0], (f32x4){0.f,0.f,0.f,0.f}, 0, 0, 0);
            acc1[1][nt] = __builtin_amdgcn_mfma_f32_16x16x32_f16(W1c[nt], bf1[1], (f32x4){0.f,0.f,0.f,0.f}, 0, 0, 0);
        }

        // ---- epilogue 1: bias + silu -> layer-2 B frags (in-register) ----
        half8 bf2[2][4];
        #pragma unroll
        for (int mt = 0; mt < 2; ++mt) {
            #pragma unroll
            for (int s = 0; s < 4; ++s) {
                half8 v;
                #pragma unroll
                for (int hj = 0; hj < 2; ++hj) {
                    int nt = 2 * s + hj;
                    f32x4 bb = *(const f32x4*)&sB1[nt * 16 + 4 * q];
                    #pragma unroll
                    for (int c = 0; c < 4; ++c) {
                        float x = acc1[mt][nt][c] + bb[c];
                        v[hj * 4 + c] = (_Float16)silu_f(x);
                    }
                }
                bf2[mt][s] = v;
            }
        }

        // ---- layer 2: D2[n2][m], A from LDS ----
        f32x4 acc2[2][8];
        #pragma unroll
        for (int mt = 0; mt < 2; ++mt)
            #pragma unroll
            for (int nt = 0; nt < 8; ++nt)
                acc2[mt][nt] = (f32x4){0.f, 0.f, 0.f, 0.f};
        #pragma unroll
        for (int s = 0; s < 4; ++s) {
            #pragma unroll
            for (int nt = 0; nt < 8; ++nt) {
                int n2 = nt * 16 + ln;
                int hw = n2 * 128 + ((s * 32 + q * 8) ^ ((n2 & 7) << 3));
                half8 a2 = *(const half8*)&sW2p[hw];
                acc2[0][nt] = __builtin_amdgcn_mfma_f32_16x16x32_f16(a2, bf2[0][s], acc2[0][nt], 0, 0, 0);
                acc2[1][nt] = __builtin_amdgcn_mfma_f32_16x16x32_f16(a2, bf2[1][s], acc2[1][nt], 0, 0, 0);
            }
        }

        // ---- epilogue 2: bias + silu -> layer-3 B frags ----
        half8 bf3[2][4];
        #pragma unroll
        for (int mt = 0; mt < 2; ++mt) {
            #pragma unroll
            for (int s = 0; s < 4; ++s) {
                half8 v;
                #pragma unroll
                for (int hj = 0; hj < 2; ++hj) {
                    int nt = 2 * s + hj;
                    f32x4 bb = *(const f32x4*)&sB2[nt * 16 + 4 * q];
                    #pragma unroll
                    for (int c = 0; c < 4; ++c) {
                        float x = acc2[mt][nt][c] + bb[c];
                        v[hj * 4 + c] = (_Float16)silu_f(x);
                    }
                }
                bf3[mt][s] = v;
            }
        }

        // ---- layer 3: p^T[n3][m], n3 = 0..5 valid ----
        f32x4 acc3[2];
        acc3[0] = (f32x4){0.f, 0.f, 0.f, 0.f};
        acc3[1] = (f32x4){0.f, 0.f, 0.f, 0.f};
        #pragma unroll
        for (int s = 0; s < 4; ++s) {
            acc3[0] = __builtin_amdgcn_mfma_f32_16x16x32_f16(W3c[s], bf3[0][s], acc3[0], 0, 0, 0);
            acc3[1] = __builtin_amdgcn_mfma_f32_16x16x32_f16(W3c[s], bf3[1][s], acc3[1], 0, 0, 0);
        }

        // ---- epilogue 3: params -> wave-private LDS bounce ----
        #pragma unroll
        for (int mt = 0; mt < 2; ++mt) {
            #pragma unroll
            for (int r = 0; r < 4; ++r) {
                int n3 = 4 * q + r;
                if (n3 < 6) sP[w][mt * 16 + ln][n3] = acc3[mt][r] + b3c[r];
            }
        }
        __syncthreads();  // make wave's sP writes visible (cross-lane)

        // ---- quantum circuit sim: lanes 0..31, one batch row each ----
        if (lane < 32) {
            const float* pr = &sP[w][lane][0];
            float ar = 1.f, ai = 0.f, br = 0.f, bi = 0.f;
            #pragma unroll
            for (int l = 0; l < 3; ++l) {
                float th = pr[2 * l] * 0.5f;
                float ph = pr[2 * l + 1] * 0.5f;
                float s1, c1, se, ce;
                __sincosf(th, &s1, &c1);
                float a1r = c1 * ar - s1 * br, a1i = c1 * ai - s1 * bi;
                float b1r = s1 * ar + c1 * br, b1i = s1 * ai + c1 * bi;
                __sincosf(ph, &se, &ce);
                ar = ce * a1r + se * a1i; ai = ce * a1i - se * a1r;
                br = ce * b1r - se * b1i; bi = ce * b1i + se * b1r;
            }
            int m = rowb + lane;
            out[3 * m + 0] = 2.f * (ar * br + ai * bi);
            out[3 * m + 1] = 2.f * (ar * bi - ai * br);
            out[3 * m + 2] = ar * ar + ai * ai - br * br - bi * bi;
        }
        __syncthreads();  // protect sP reads from next tile's writes
    }
}

extern "C" void kernel_launch(void* const* d_in, const int* in_sizes, int n_in,
                              void* d_out, int out_size, void* d_ws, size_t ws_size,
                              hipStream_t stream) {
    const float* t  = (const float*)d_in[0];
    const float* bl = (const float*)d_in[1];
    const float* W1 = (const float*)d_in[2];
    const float* b1 = (const float*)d_in[3];
    const float* W2 = (const float*)d_in[4];
    const float* b2 = (const float*)d_in[5];
    const float* W3 = (const float*)d_in[6];
    const float* b3 = (const float*)d_in[7];
    qvf_kernel<<<NBLOCKS, 256, 0, stream>>>(t, bl, W1, b1, W2, b2, W3, b3, (float*)d_out);
}